// Round 9
// baseline (1088.592 us; speedup 1.0000x reference)
//
#include <hip/hip_runtime.h>

typedef short bf16x8 __attribute__((ext_vector_type(8)));
typedef float f32x4 __attribute__((ext_vector_type(4)));
typedef unsigned short us8 __attribute__((ext_vector_type(8)));

__device__ __forceinline__ unsigned short f2bf(float f) {
    unsigned int u = __float_as_uint(f);
    u += 0x7fffu + ((u >> 16) & 1u);   // round-to-nearest-even
    return (unsigned short)(u >> 16);
}

// raw barrier: does NOT drain vmcnt (in-flight global->VGPR loads survive);
// lgkmcnt(0) makes ds_writes visible; sched_barrier pins ordering (rule #18).
__device__ __forceinline__ void hard_barrier() {
    asm volatile("s_waitcnt lgkmcnt(0)" ::: "memory");
    __builtin_amdgcn_sched_barrier(0);
    __builtin_amdgcn_s_barrier();
    __builtin_amdgcn_sched_barrier(0);
}

// ---- transpose + cast fp32 -> bf16 bits: out[Cc][R] = cast(in[R][Cc]) ----
__global__ __launch_bounds__(256) void transpose_cast_kernel(
    const float* __restrict__ in, unsigned short* __restrict__ out, int R, int Cc) {
    __shared__ alignas(16) unsigned short sT[64][65];
    const int r0 = blockIdx.x * 64, c0 = blockIdx.y * 64;
    const int t = threadIdx.x;
#pragma unroll
    for (int p = 0; p < 16; ++p) {
        int flat = p * 256 + t;
        int r = flat >> 6, c = flat & 63;
        sT[c][r] = f2bf(in[(size_t)(r0 + r) * Cc + (c0 + c)]);
    }
    __syncthreads();
#pragma unroll
    for (int p = 0; p < 16; ++p) {
        int flat = p * 256 + t;
        int c = flat >> 6, r = flat & 63;
        out[(size_t)(c0 + c) * R + (r0 + r)] = sT[c][r];
    }
}

// ---- small MFMA GEMM (BM=64, 4 waves): C[M][N] = A[M][K] @ (BT[N][K])^T ----
// AMODE 1: A fp32 -> bf16 during staging.
// AMODE 2: A = relu(sum of 4 fp32 slabs, stride aslab) -> bf16 during staging.
// TOUT: write bf16 transposed C[N][M].
template<int BN, int WM, int WN, int AMODE, bool TOUT, typename OutT>
__global__ __launch_bounds__(256) void gemm_kernel(
    const void* __restrict__ Aptr, const unsigned short* __restrict__ BT,
    OutT* __restrict__ C, int M, int N, int K, long aslab) {
    constexpr int BM = 64, BK = 64, LDW = 72;
    constexpr int MF = BM / WM / 16;
    constexpr int NF = BN / WN / 16;
    __shared__ alignas(16) unsigned short sA[BM * LDW];
    __shared__ alignas(16) unsigned short sB[BN * LDW];
    const int t = threadIdx.x;
    const int w = t >> 6, l = t & 63;
    const int wr = w / WN, wc = w % WN;
    const int m0 = blockIdx.x * BM;

    f32x4 acc[MF][NF] = {};

    for (int k0 = 0; k0 < K; k0 += BK) {
        const float* A32 = (const float*)Aptr;
#pragma unroll
        for (int p = 0; p < 4; ++p) {
            int flat = p * 256 + t;
            int row = flat >> 4, c4 = flat & 15;
            size_t base = (size_t)(m0 + row) * K + k0 + c4 * 4;
            float4 v = *(const float4*)&A32[base];
            if constexpr (AMODE == 2) {
                float4 b = *(const float4*)&A32[aslab + base];
                float4 c = *(const float4*)&A32[2 * aslab + base];
                float4 d = *(const float4*)&A32[3 * aslab + base];
                v.x = fmaxf(v.x + b.x + c.x + d.x, 0.f);
                v.y = fmaxf(v.y + b.y + c.y + d.y, 0.f);
                v.z = fmaxf(v.z + b.z + c.z + d.z, 0.f);
                v.w = fmaxf(v.w + b.w + c.w + d.w, 0.f);
            }
            ushort4 o = make_ushort4(f2bf(v.x), f2bf(v.y), f2bf(v.z), f2bf(v.w));
            *(ushort4*)&sA[row * LDW + c4 * 4] = o;
        }
#pragma unroll
        for (int p = 0; p < BN * 8 / 256; ++p) {
            int flat = p * 256 + t;
            int row = flat >> 3, c8 = flat & 7;
            us8 v = *(const us8*)&BT[(size_t)row * K + k0 + c8 * 8];
            *(us8*)&sB[row * LDW + c8 * 8] = v;
        }
        __syncthreads();
#pragma unroll
        for (int kk = 0; kk < BK; kk += 32) {
            bf16x8 av[MF], bv[NF];
#pragma unroll
            for (int m = 0; m < MF; ++m)
                av[m] = *(const bf16x8*)&sA[(wr * (BM / WM) + m * 16 + (l & 15)) * LDW + kk + (l >> 4) * 8];
#pragma unroll
            for (int n = 0; n < NF; ++n)
                bv[n] = *(const bf16x8*)&sB[(wc * (BN / WN) + n * 16 + (l & 15)) * LDW + kk + (l >> 4) * 8];
#pragma unroll
            for (int m = 0; m < MF; ++m)
#pragma unroll
                for (int n = 0; n < NF; ++n)
                    acc[m][n] = __builtin_amdgcn_mfma_f32_16x16x32_bf16(av[m], bv[n], acc[m][n], 0, 0, 0);
        }
        __syncthreads();
    }

#pragma unroll
    for (int m = 0; m < MF; ++m) {
#pragma unroll
        for (int n = 0; n < NF; ++n) {
            const int col = wc * (BN / WN) + n * 16 + (l & 15);
            const int rb = m0 + wr * (BM / WM) + m * 16 + ((l >> 4) << 2);
            float v0 = acc[m][n][0], v1 = acc[m][n][1], v2 = acc[m][n][2], v3 = acc[m][n][3];
            if constexpr (TOUT) {
                ushort4 o = make_ushort4(f2bf(v0), f2bf(v1), f2bf(v2), f2bf(v3));
                *(ushort4*)((unsigned short*)C + (size_t)col * M + rb) = o;
            } else {
                C[(size_t)(rb + 0) * N + col] = (OutT)v0;
                C[(size_t)(rb + 1) * N + col] = (OutT)v1;
                C[(size_t)(rb + 2) * N + col] = (OutT)v2;
                C[(size_t)(rb + 3) * N + col] = (OutT)v3;
            }
        }
    }
}

// ---- big adj-streaming GEMM: reg-staged, DEPTH-2 load pipeline, LDS dbuf,
// raw non-vmcnt-draining barrier, XCD-swizzled block ids ----
// C (fp32 K-split partial slab z) = adj[M][K] @ (BT[N][K])^T
// Step t: LOAD(t+2)->regset[t&1]; compute(buf[t&1]); WRITE(regset[(t+1)&1] ->
// buf[(t+1)&1]) [compiler emits counted vmcnt: only t+2's loads outstanding];
// hard_barrier. Loads get ~2 full steps of latency cover.
template<int BM, int BN, int WM, int WN, int THREADS>
__global__ __launch_bounds__(THREADS, 4) void pipe_gemm_kernel(
    const float* __restrict__ A, const unsigned short* __restrict__ BT,
    float* __restrict__ C, int M, int N, int K) {
    constexpr int BK = 64, LDW = 72;
    constexpr int MF = BM / WM / 16, NF = BN / WN / 16;
    constexpr int ACH = BM * BK / 4 / THREADS;   // float4 per thread (A)
    constexpr int BCH = BN * BK / 8 / THREADS;   // us8 per thread (B)
    static_assert(ACH * THREADS * 4 == BM * BK && BCH * THREADS * 8 == BN * BK, "split");
    __shared__ alignas(16) unsigned short sA[2][BM * LDW];
    __shared__ alignas(16) unsigned short sB[2][BN * LDW];
    const int t = threadIdx.x, w = t >> 6, l = t & 63;
    const int wr = w / WN, wc = w % WN;
    // XCD-aware bijective remap (nwg % 8 == 0): each XCD gets a contiguous
    // chunk -> all its blocks share one z (one L2-resident B slice).
    const int nx = gridDim.x;
    const int lin = blockIdx.x + nx * blockIdx.z;
    const int cpx = (nx * gridDim.z) >> 3;
    const int sw = (lin & 7) * cpx + (lin >> 3);
    const int bx = sw % nx, bz = sw / nx;
    const int m0 = bx * BM;
    const int klen = K / gridDim.z, kbeg = bz * klen;
    const int NT = klen / BK;
    float* Cp = C + (size_t)bz * M * N;

    float4 ar[2][ACH];
    us8 br[2][BCH];

    auto LOAD = [&](int set, int k0) {
#pragma unroll
        for (int p = 0; p < ACH; ++p) {
            int flat = p * THREADS + t, row = flat >> 4, c4 = flat & 15;
            ar[set][p] = *(const float4*)&A[(size_t)(m0 + row) * K + k0 + c4 * 4];
        }
#pragma unroll
        for (int p = 0; p < BCH; ++p) {
            int flat = p * THREADS + t, row = flat >> 3, c8 = flat & 7;
            br[set][p] = *(const us8*)&BT[(size_t)row * K + k0 + c8 * 8];
        }
    };
    auto WRITE = [&](int set, int buf) {
#pragma unroll
        for (int p = 0; p < ACH; ++p) {
            int flat = p * THREADS + t, row = flat >> 4, c4 = flat & 15;
            float4 v = ar[set][p];
            *(ushort4*)&sA[buf][row * LDW + c4 * 4] =
                make_ushort4(f2bf(v.x), f2bf(v.y), f2bf(v.z), f2bf(v.w));
        }
#pragma unroll
        for (int p = 0; p < BCH; ++p) {
            int flat = p * THREADS + t, row = flat >> 3, c8 = flat & 7;
            *(us8*)&sB[buf][row * LDW + c8 * 8] = br[set][p];
        }
    };

    f32x4 acc[MF][NF] = {};

    LOAD(0, kbeg);
    if (NT > 1) LOAD(1, kbeg + BK);
    WRITE(0, 0);                   // compiler waits tile0's loads (counted)
    hard_barrier();

    for (int tt = 0; tt < NT; ++tt) {
        if (tt + 2 < NT) LOAD(tt & 1, kbeg + (tt + 2) * BK);
        __builtin_amdgcn_sched_barrier(0);   // keep load issue ahead of compute
        const int cur = tt & 1;
#pragma unroll
        for (int kk = 0; kk < BK; kk += 32) {
            bf16x8 av[MF], bv[NF];
#pragma unroll
            for (int m = 0; m < MF; ++m)
                av[m] = *(const bf16x8*)&sA[cur][(wr * (BM / WM) + m * 16 + (l & 15)) * LDW + kk + (l >> 4) * 8];
#pragma unroll
            for (int n = 0; n < NF; ++n)
                bv[n] = *(const bf16x8*)&sB[cur][(wc * (BN / WN) + n * 16 + (l & 15)) * LDW + kk + (l >> 4) * 8];
#pragma unroll
            for (int m = 0; m < MF; ++m)
#pragma unroll
                for (int n = 0; n < NF; ++n)
                    acc[m][n] = __builtin_amdgcn_mfma_f32_16x16x32_bf16(av[m], bv[n], acc[m][n], 0, 0, 0);
        }
        if (tt + 1 < NT) WRITE((tt + 1) & 1, cur ^ 1);
        hard_barrier();            // no vmcnt drain: t+2's loads stay in flight
    }

#pragma unroll
    for (int m = 0; m < MF; ++m)
#pragma unroll
        for (int n = 0; n < NF; ++n) {
            const int col = wc * (BN / WN) + n * 16 + (l & 15);
            const int rb = m0 + wr * (BM / WM) + m * 16 + ((l >> 4) << 2);
#pragma unroll
            for (int j = 0; j < 4; ++j)
                Cp[(size_t)(rb + j) * N + col] = acc[m][n][j];
        }
}

// ---- head: reduce 8 fp32 partial slabs of o[8192][64], then log_softmax rows ----
__global__ __launch_bounds__(256) void head2_kernel(
    const float* __restrict__ p, float* __restrict__ out, int M) {
    const int t = threadIdx.x, w = t >> 6, l = t & 63;
    const size_t stride = (size_t)M * 64;
#pragma unroll
    for (int rr = 0; rr < 4; ++rr) {
        int i = blockIdx.x * 16 + w * 4 + rr;
        size_t off = (size_t)i * 64 + l;
        float v = 0.f;
#pragma unroll
        for (int s = 0; s < 8; ++s) v += p[s * stride + off];
        float mx = v;
#pragma unroll
        for (int o = 32; o; o >>= 1) mx = fmaxf(mx, __shfl_xor(mx, o));
        float d0 = v - mx;
        float e = __expf(d0);
#pragma unroll
        for (int o = 32; o; o >>= 1) e += __shfl_xor(e, o);
        out[off] = d0 - __logf(e);
    }
}

extern "C" void kernel_launch(void* const* d_in, const int* in_sizes, int n_in,
                              void* d_out, int out_size, void* d_ws, size_t ws_size,
                              hipStream_t stream) {
    const float* adj = (const float*)d_in[0];
    const float* x   = (const float*)d_in[1];
    const float* W1  = (const float*)d_in[2];
    const float* W2  = (const float*)d_in[3];
    float* out = (float*)d_out;

    const int M = 8192, K = 8192;
    char* ws = (char*)d_ws;
    // ws layout (~55.8 MB; ws_size ~1 GB):
    float*          pbuf1 = (float*)ws;                        // 32 MB: 4 slabs t1 partials [8192][256]
    float*          pbuf2 = (float*)(ws + 33554432);           // 16 MB: 8 slabs o partials  [8192][64]
    unsigned short* zT    = (unsigned short*)(ws + 50331648);  //  4 MB: z^T  bf16 [256][8192]
    unsigned short* hwT   = (unsigned short*)(ws + 54525952);  //  1 MB: hw^T bf16 [64][8192]
    unsigned short* W1T   = (unsigned short*)(ws + 55574528);  // 128 KB
    unsigned short* W2T   = (unsigned short*)(ws + 55705600);  // 32 KB

    transpose_cast_kernel<<<dim3(4, 4), 256, 0, stream>>>(W1, W1T, 256, 256);
    transpose_cast_kernel<<<dim3(4, 1), 256, 0, stream>>>(W2, W2T, 256, 64);
    // z^T = (x @ W1)^T, bf16
    gemm_kernel<256, 1, 4, 1, true, unsigned short>
        <<<dim3(M / 64), 256, 0, stream>>>(x, W1T, zT, M, 256, 256, 0);
    // t1 partials = adj @ z  (K-split 4; 256 blocks, 16 waves, LDS 110.6 KB)
    pipe_gemm_kernel<128, 256, 4, 4, 1024>
        <<<dim3(M / 128, 1, 4), 1024, 0, stream>>>(adj, zT, pbuf1, M, 256, K);
    // hw^T = (relu(sum of 4 t1 slabs) @ W2)^T, bf16
    gemm_kernel<64, 2, 2, 2, true, unsigned short>
        <<<dim3(M / 64), 256, 0, stream>>>(pbuf1, W2T, hwT, M, 64, 256, (long)M * 256);
    // o partials = adj @ hw  (K-split 8; 512 blocks, LDS 55.3 KB -> 2 blocks/CU)
    pipe_gemm_kernel<128, 64, 4, 2, 512>
        <<<dim3(M / 128, 1, 8), 512, 0, stream>>>(adj, hwT, pbuf2, M, 64, K);
    head2_kernel<<<dim3(M / 16), 256, 0, stream>>>(pbuf2, out, M);
}

// Round 10
// 157.369 us; speedup vs baseline: 6.9174x; 6.9174x over previous
//
#include <hip/hip_runtime.h>

typedef short bf16x8 __attribute__((ext_vector_type(8)));
typedef float f32x4 __attribute__((ext_vector_type(4)));
typedef unsigned short us8 __attribute__((ext_vector_type(8)));

__device__ __forceinline__ unsigned short f2bf(float f) {
    unsigned int u = __float_as_uint(f);
    u += 0x7fffu + ((u >> 16) & 1u);   // round-to-nearest-even
    return (unsigned short)(u >> 16);
}

// raw barrier: does NOT drain vmcnt (in-flight global->VGPR loads survive);
// lgkmcnt(0) makes ds_writes visible; sched_barrier pins ordering (rule #18).
__device__ __forceinline__ void hard_barrier() {
    asm volatile("s_waitcnt lgkmcnt(0)" ::: "memory");
    __builtin_amdgcn_sched_barrier(0);
    __builtin_amdgcn_s_barrier();
    __builtin_amdgcn_sched_barrier(0);
}

// ---- transpose + cast fp32 -> bf16 bits: out[Cc][R] = cast(in[R][Cc]) ----
__global__ __launch_bounds__(256) void transpose_cast_kernel(
    const float* __restrict__ in, unsigned short* __restrict__ out, int R, int Cc) {
    __shared__ alignas(16) unsigned short sT[64][65];
    const int r0 = blockIdx.x * 64, c0 = blockIdx.y * 64;
    const int t = threadIdx.x;
#pragma unroll
    for (int p = 0; p < 16; ++p) {
        int flat = p * 256 + t;
        int r = flat >> 6, c = flat & 63;
        sT[c][r] = f2bf(in[(size_t)(r0 + r) * Cc + (c0 + c)]);
    }
    __syncthreads();
#pragma unroll
    for (int p = 0; p < 16; ++p) {
        int flat = p * 256 + t;
        int c = flat >> 6, r = flat & 63;
        out[(size_t)(c0 + c) * R + (r0 + r)] = sT[c][r];
    }
}

// ---- small MFMA GEMM (BM=64, 4 waves): C[M][N] = A[M][K] @ (BT[N][K])^T ----
// AMODE 1: A fp32 -> bf16 during staging.
// AMODE 2: A = relu(sum of 4 fp32 slabs, stride aslab) -> bf16 during staging.
// TOUT: write bf16 transposed C[N][M].
template<int BN, int WM, int WN, int AMODE, bool TOUT, typename OutT>
__global__ __launch_bounds__(256) void gemm_kernel(
    const void* __restrict__ Aptr, const unsigned short* __restrict__ BT,
    OutT* __restrict__ C, int M, int N, int K, long aslab) {
    constexpr int BM = 64, BK = 64, LDW = 72;
    constexpr int MF = BM / WM / 16;
    constexpr int NF = BN / WN / 16;
    __shared__ alignas(16) unsigned short sA[BM * LDW];
    __shared__ alignas(16) unsigned short sB[BN * LDW];
    const int t = threadIdx.x;
    const int w = t >> 6, l = t & 63;
    const int wr = w / WN, wc = w % WN;
    const int m0 = blockIdx.x * BM;

    f32x4 acc[MF][NF] = {};

    for (int k0 = 0; k0 < K; k0 += BK) {
        const float* A32 = (const float*)Aptr;
#pragma unroll
        for (int p = 0; p < 4; ++p) {
            int flat = p * 256 + t;
            int row = flat >> 4, c4 = flat & 15;
            size_t base = (size_t)(m0 + row) * K + k0 + c4 * 4;
            float4 v = *(const float4*)&A32[base];
            if constexpr (AMODE == 2) {
                float4 b = *(const float4*)&A32[aslab + base];
                float4 c = *(const float4*)&A32[2 * aslab + base];
                float4 d = *(const float4*)&A32[3 * aslab + base];
                v.x = fmaxf(v.x + b.x + c.x + d.x, 0.f);
                v.y = fmaxf(v.y + b.y + c.y + d.y, 0.f);
                v.z = fmaxf(v.z + b.z + c.z + d.z, 0.f);
                v.w = fmaxf(v.w + b.w + c.w + d.w, 0.f);
            }
            ushort4 o = make_ushort4(f2bf(v.x), f2bf(v.y), f2bf(v.z), f2bf(v.w));
            *(ushort4*)&sA[row * LDW + c4 * 4] = o;
        }
#pragma unroll
        for (int p = 0; p < BN * 8 / 256; ++p) {
            int flat = p * 256 + t;
            int row = flat >> 3, c8 = flat & 7;
            us8 v = *(const us8*)&BT[(size_t)row * K + k0 + c8 * 8];
            *(us8*)&sB[row * LDW + c8 * 8] = v;
        }
        __syncthreads();
#pragma unroll
        for (int kk = 0; kk < BK; kk += 32) {
            bf16x8 av[MF], bv[NF];
#pragma unroll
            for (int m = 0; m < MF; ++m)
                av[m] = *(const bf16x8*)&sA[(wr * (BM / WM) + m * 16 + (l & 15)) * LDW + kk + (l >> 4) * 8];
#pragma unroll
            for (int n = 0; n < NF; ++n)
                bv[n] = *(const bf16x8*)&sB[(wc * (BN / WN) + n * 16 + (l & 15)) * LDW + kk + (l >> 4) * 8];
#pragma unroll
            for (int m = 0; m < MF; ++m)
#pragma unroll
                for (int n = 0; n < NF; ++n)
                    acc[m][n] = __builtin_amdgcn_mfma_f32_16x16x32_bf16(av[m], bv[n], acc[m][n], 0, 0, 0);
        }
        __syncthreads();
    }

#pragma unroll
    for (int m = 0; m < MF; ++m) {
#pragma unroll
        for (int n = 0; n < NF; ++n) {
            const int col = wc * (BN / WN) + n * 16 + (l & 15);
            const int rb = m0 + wr * (BM / WM) + m * 16 + ((l >> 4) << 2);
            float v0 = acc[m][n][0], v1 = acc[m][n][1], v2 = acc[m][n][2], v3 = acc[m][n][3];
            if constexpr (TOUT) {
                ushort4 o = make_ushort4(f2bf(v0), f2bf(v1), f2bf(v2), f2bf(v3));
                *(ushort4*)((unsigned short*)C + (size_t)col * M + rb) = o;
            } else {
                C[(size_t)(rb + 0) * N + col] = (OutT)v0;
                C[(size_t)(rb + 1) * N + col] = (OutT)v1;
                C[(size_t)(rb + 2) * N + col] = (OutT)v2;
                C[(size_t)(rb + 3) * N + col] = (OutT)v3;
            }
        }
    }
}

// ---- big adj-streaming GEMM: reg-staged DEPTH-2 pipeline with STATIC register
// sets (rule #20: no runtime-indexed reg arrays), LDS dbuf, raw barrier, XCD
// swizzle. C (fp32 K-split partial slab z) = adj[M][K] @ (BT[N][K])^T ----
template<int BM, int BN, int WM, int WN, int THREADS>
__global__ __launch_bounds__(THREADS, 4) void pipe_gemm_kernel(
    const float* __restrict__ A, const unsigned short* __restrict__ BT,
    float* __restrict__ C, int M, int N, int K) {
    constexpr int BK = 64, LDW = 72;
    constexpr int MF = BM / WM / 16, NF = BN / WN / 16;
    constexpr int ACH = BM * BK / 4 / THREADS;   // float4 per thread (A)
    constexpr int BCH = BN * BK / 8 / THREADS;   // us8 per thread (B)
    static_assert(ACH * THREADS * 4 == BM * BK && BCH * THREADS * 8 == BN * BK, "split");
    __shared__ alignas(16) unsigned short sA[2][BM * LDW];
    __shared__ alignas(16) unsigned short sB[2][BN * LDW];
    const int t = threadIdx.x, w = t >> 6, l = t & 63;
    const int wr = w / WN, wc = w % WN;
    // XCD-aware bijective remap (nwg % 8 == 0): each XCD gets a contiguous
    // chunk -> all its blocks share one K-slice (L2-resident B slice).
    const int nx = gridDim.x;
    const int lin = blockIdx.x + nx * blockIdx.z;
    const int cpx = (nx * gridDim.z) >> 3;
    const int sw = (lin & 7) * cpx + (lin >> 3);
    const int bx = sw % nx, bz = sw / nx;
    const int m0 = bx * BM;
    const int klen = K / gridDim.z, kbeg = bz * klen;
    const int NT = klen / BK;
    float* Cp = C + (size_t)bz * M * N;

    float4 a0[ACH], a1[ACH];     // two STATIC register sets (no runtime index)
    us8 b0[BCH], b1[BCH];

    auto LOAD = [&](float4 (&ar)[ACH], us8 (&br)[BCH], int k0) {
#pragma unroll
        for (int p = 0; p < ACH; ++p) {
            int flat = p * THREADS + t, row = flat >> 4, c4 = flat & 15;
            ar[p] = *(const float4*)&A[(size_t)(m0 + row) * K + k0 + c4 * 4];
        }
#pragma unroll
        for (int p = 0; p < BCH; ++p) {
            int flat = p * THREADS + t, row = flat >> 3, c8 = flat & 7;
            br[p] = *(const us8*)&BT[(size_t)row * K + k0 + c8 * 8];
        }
    };
    auto WRITE = [&](float4 (&ar)[ACH], us8 (&br)[BCH], int buf) {
#pragma unroll
        for (int p = 0; p < ACH; ++p) {
            int flat = p * THREADS + t, row = flat >> 4, c4 = flat & 15;
            float4 v = ar[p];
            *(ushort4*)&sA[buf][row * LDW + c4 * 4] =
                make_ushort4(f2bf(v.x), f2bf(v.y), f2bf(v.z), f2bf(v.w));
        }
#pragma unroll
        for (int p = 0; p < BCH; ++p) {
            int flat = p * THREADS + t, row = flat >> 3, c8 = flat & 7;
            *(us8*)&sB[buf][row * LDW + c8 * 8] = br[p];
        }
    };

    f32x4 acc[MF][NF] = {};

    auto COMPUTE = [&](int buf) {
#pragma unroll
        for (int kk = 0; kk < BK; kk += 32) {
            bf16x8 av[MF], bv[NF];
#pragma unroll
            for (int m = 0; m < MF; ++m)
                av[m] = *(const bf16x8*)&sA[buf][(wr * (BM / WM) + m * 16 + (l & 15)) * LDW + kk + (l >> 4) * 8];
#pragma unroll
            for (int n = 0; n < NF; ++n)
                bv[n] = *(const bf16x8*)&sB[buf][(wc * (BN / WN) + n * 16 + (l & 15)) * LDW + kk + (l >> 4) * 8];
#pragma unroll
            for (int m = 0; m < MF; ++m)
#pragma unroll
                for (int n = 0; n < NF; ++n)
                    acc[m][n] = __builtin_amdgcn_mfma_f32_16x16x32_bf16(av[m], bv[n], acc[m][n], 0, 0, 0);
        }
    };

    // prologue: tiles 0,1 in flight; tile 0 staged to LDS buf0
    LOAD(a0, b0, kbeg);
    LOAD(a1, b1, kbeg + BK);
    WRITE(a0, b0, 0);            // counted wait: only tile-1 loads outstanding
    hard_barrier();

    for (int tt = 0; tt < NT; tt += 2) {
        // even step: compute buf0; a0/b0 free -> load tile tt+2 into them
        if (tt + 2 < NT) LOAD(a0, b0, kbeg + (tt + 2) * BK);
        __builtin_amdgcn_sched_barrier(0);
        COMPUTE(0);
        if (tt + 1 < NT) WRITE(a1, b1, 1);   // counted wait: tt+2 stays in flight
        hard_barrier();
        if (tt + 1 < NT) {
            // odd step: compute buf1; a1/b1 free -> load tile tt+3
            if (tt + 3 < NT) LOAD(a1, b1, kbeg + (tt + 3) * BK);
            __builtin_amdgcn_sched_barrier(0);
            COMPUTE(1);
            if (tt + 2 < NT) WRITE(a0, b0, 0);
            hard_barrier();
        }
    }

#pragma unroll
    for (int m = 0; m < MF; ++m)
#pragma unroll
        for (int n = 0; n < NF; ++n) {
            const int col = wc * (BN / WN) + n * 16 + (l & 15);
            const int rb = m0 + wr * (BM / WM) + m * 16 + ((l >> 4) << 2);
#pragma unroll
            for (int j = 0; j < 4; ++j)
                Cp[(size_t)(rb + j) * N + col] = acc[m][n][j];
        }
}

// ---- head: reduce 8 fp32 partial slabs of o[8192][64], then log_softmax rows ----
__global__ __launch_bounds__(256) void head2_kernel(
    const float* __restrict__ p, float* __restrict__ out, int M) {
    const int t = threadIdx.x, w = t >> 6, l = t & 63;
    const size_t stride = (size_t)M * 64;
#pragma unroll
    for (int rr = 0; rr < 4; ++rr) {
        int i = blockIdx.x * 16 + w * 4 + rr;
        size_t off = (size_t)i * 64 + l;
        float v = 0.f;
#pragma unroll
        for (int s = 0; s < 8; ++s) v += p[s * stride + off];
        float mx = v;
#pragma unroll
        for (int o = 32; o; o >>= 1) mx = fmaxf(mx, __shfl_xor(mx, o));
        float d0 = v - mx;
        float e = __expf(d0);
#pragma unroll
        for (int o = 32; o; o >>= 1) e += __shfl_xor(e, o);
        out[off] = d0 - __logf(e);
    }
}

extern "C" void kernel_launch(void* const* d_in, const int* in_sizes, int n_in,
                              void* d_out, int out_size, void* d_ws, size_t ws_size,
                              hipStream_t stream) {
    const float* adj = (const float*)d_in[0];
    const float* x   = (const float*)d_in[1];
    const float* W1  = (const float*)d_in[2];
    const float* W2  = (const float*)d_in[3];
    float* out = (float*)d_out;

    const int M = 8192, K = 8192;
    char* ws = (char*)d_ws;
    // ws layout (~55.8 MB; ws_size ~1 GB):
    float*          pbuf1 = (float*)ws;                        // 32 MB: 4 slabs t1 partials [8192][256]
    float*          pbuf2 = (float*)(ws + 33554432);           // 16 MB: 8 slabs o partials  [8192][64]
    unsigned short* zT    = (unsigned short*)(ws + 50331648);  //  4 MB: z^T  bf16 [256][8192]
    unsigned short* hwT   = (unsigned short*)(ws + 54525952);  //  1 MB: hw^T bf16 [64][8192]
    unsigned short* W1T   = (unsigned short*)(ws + 55574528);  // 128 KB
    unsigned short* W2T   = (unsigned short*)(ws + 55705600);  // 32 KB

    transpose_cast_kernel<<<dim3(4, 4), 256, 0, stream>>>(W1, W1T, 256, 256);
    transpose_cast_kernel<<<dim3(4, 1), 256, 0, stream>>>(W2, W2T, 256, 64);
    // z^T = (x @ W1)^T, bf16
    gemm_kernel<256, 1, 4, 1, true, unsigned short>
        <<<dim3(M / 64), 256, 0, stream>>>(x, W1T, zT, M, 256, 256, 0);
    // t1 partials = adj @ z  (K-split 4; 256 blocks, 16 waves, LDS 110.6 KB)
    pipe_gemm_kernel<128, 256, 4, 4, 1024>
        <<<dim3(M / 128, 1, 4), 1024, 0, stream>>>(adj, zT, pbuf1, M, 256, K);
    // hw^T = (relu(sum of 4 t1 slabs) @ W2)^T, bf16
    gemm_kernel<64, 2, 2, 2, true, unsigned short>
        <<<dim3(M / 64), 256, 0, stream>>>(pbuf1, W2T, hwT, M, 64, 256, (long)M * 256);
    // o partials = adj @ hw  (K-split 8; 512 blocks, LDS 55.3 KB -> 2 blocks/CU)
    pipe_gemm_kernel<128, 64, 4, 2, 512>
        <<<dim3(M / 128, 1, 8), 512, 0, stream>>>(adj, hwT, pbuf2, M, 64, K);
    head2_kernel<<<dim3(M / 16), 256, 0, stream>>>(pbuf2, out, M);
}